// Round 7
// baseline (43.654 us; speedup 1.0000x reference)
//
#include <hip/hip_runtime.h>

// Length regulator (fully fused, single kernel, persistent-style blocks):
//   out[b, m, :] = x[b, searchsorted_right(cum(duration[b]), m), :]  for m < mel_len[b]
//   out[b, m, :] = 0                                                 otherwise
//   mel_len[b]   = sum_t duration[b, t]   (stored as float in d_out tail)
//
// Geometry (from setup_inputs): B=32, T=512, D=384, max_len=3584.
// Fast path assumes T==512, D4==96, tot%8192==0; generic fallback kept.
//
// Ledger: R4 (336x32 blocks, 1024 f4/block) = 35.15us best. R5 (wave0 scan,
// 2048/block) = 40.7 REGRESS. R6 (XCD swizzle) = 37.2 REGRESS.
// R7: isolate the prologue-redundancy theory cleanly: same all-thread scan,
// but 8x fewer blocks (42x32=1344, all co-resident on 256 CUs), each block
// scans once and copies 8192 float4s. If flat vs R4 -> mixed-BW roofline.

#define LR_B 32
#define LR_T 512

typedef float f32x4 __attribute__((ext_vector_type(4)));

// ---------------------------------------------------------------------------
// Fused kernel: block = (chunk-of-8192-float4s, batch). 256 threads.
//  1. load 512 durations -> LDS, Hillis-Steele inclusive scan (2 elems/thread)
//  2. threads 0..NF-1 (NF<=87) binary-search the block's frames -> idx_s
//  3. copy loop: 8 outer x 4 inner (unrolled) float4s, nontemporal stores
// ---------------------------------------------------------------------------
template <int D4C>
__global__ __launch_bounds__(256) void lr_fused_kernel(
        const f32x4* __restrict__ x4,
        const int* __restrict__ dur,
        f32x4* __restrict__ out4,
        float* __restrict__ mel_out,
        int T, int max_len) {
    __shared__ int s[LR_T];
    __shared__ int idx_s[96];

    const int b  = blockIdx.y;
    const int bx = blockIdx.x;
    const int t  = threadIdx.x;

    // --- 1. scan of duration[b, :] (512 elems, 256 threads, 2 per thread) ---
    const int* __restrict__ db = dur + b * LR_T;
    s[t]       = db[t];
    s[t + 256] = db[t + 256];
    __syncthreads();
    #pragma unroll
    for (int off = 1; off < LR_T; off <<= 1) {
        const int p1 = t + 256;
        const int a0 = (t >= off) ? s[t - off] : 0;
        const int a1 = s[p1 - off];            // p1 >= 256 >= off always
        __syncthreads();
        s[t]  += a0;
        s[p1] += a1;
        __syncthreads();
    }
    const int total = s[LR_T - 1];

    if (bx == 0 && t == 0) {
        mel_out[b] = (float)total;             // exact: total <= 3584 << 2^24
    }

    // --- 2. per-block frame index cache (covers all 8 chunks) ---
    const int e0 = bx * 8192;                  // first float4 element of block
    const int m0 = e0 / D4C;                   // first frame touched
    const int m1 = (e0 + 8191) / D4C;          // last frame touched
    const int NF = m1 - m0 + 1;                // <= 87 for D4C==96
    if (t < NF) {
        const int m = m0 + t;
        int r = -1;
        if (m < total) {
            int lo = 0, hi = T;
            while (lo < hi) {                  // searchsorted side='right'
                const int mid = (lo + hi) >> 1;
                if (s[mid] <= m) lo = mid + 1; else hi = mid;
            }
            r = (lo < T) ? lo : (T - 1);
        }
        idx_s[t] = r;
    }
    __syncthreads();

    // --- 3. gather-copy: 32 float4s/thread (8 outer x 4 unrolled inner) ---
    const f32x4* __restrict__ xb = x4 + (size_t)b * T * D4C;
    f32x4* __restrict__ ob = out4 + (size_t)b * (size_t)max_len * D4C;
    for (int c = 0; c < 8; ++c) {
        const int ec = e0 + c * 1024;
        #pragma unroll
        for (int j = 0; j < 4; ++j) {
            const int e  = ec + j * 256 + t;
            const int m  = e / D4C;            // compile-time divisor -> magic-mul
            const int d4 = e - m * D4C;
            const int id = idx_s[m - m0];      // LDS broadcast across lanes
            f32x4 v = (f32x4){0.f, 0.f, 0.f, 0.f};
            if (id >= 0) v = xb[id * D4C + d4];
            __builtin_nontemporal_store(v, &ob[e]);
        }
    }
}

// ---------------------------------------------------------------------------
// Generic fallback path (runtime geometry), two kernels as in R2.
// ---------------------------------------------------------------------------
__global__ void lr_scan_idx_kernel(const int* __restrict__ dur,
                                   int* __restrict__ idx,
                                   float* __restrict__ mel_out,
                                   int T, int max_len) {
    __shared__ int s[LR_T];
    const int b = blockIdx.x;
    const int t = threadIdx.x;
    s[t] = dur[b * T + t];
    __syncthreads();
    #pragma unroll
    for (int off = 1; off < LR_T; off <<= 1) {
        int add = (t >= off) ? s[t - off] : 0;
        __syncthreads();
        s[t] += add;
        __syncthreads();
    }
    const int total = s[T - 1];
    if (t == 0) mel_out[b] = (float)total;
    int* __restrict__ idxb = idx + b * max_len;
    for (int m = t; m < max_len; m += LR_T) {
        int r = -1;
        if (m < total) {
            int lo = 0, hi = T;
            while (lo < hi) {
                int mid = (lo + hi) >> 1;
                if (s[mid] <= m) lo = mid + 1; else hi = mid;
            }
            r = (lo < T) ? lo : (T - 1);
        }
        idxb[m] = r;
    }
}

__global__ void lr_copy_generic(const f32x4* __restrict__ x4,
                                const int* __restrict__ idx,
                                f32x4* __restrict__ out4,
                                int T, int max_len, int D4) {
    const int b = blockIdx.y;
    const int tot = max_len * D4;
    const int e = blockIdx.x * blockDim.x + threadIdx.x;
    if (e >= tot) return;
    const int m  = e / D4;
    const int d4 = e - m * D4;
    const int id = idx[b * max_len + m];
    f32x4 v = (f32x4){0.f, 0.f, 0.f, 0.f};
    if (id >= 0) v = x4[((size_t)b * T + id) * D4 + d4];
    out4[(size_t)b * tot + e] = v;
}

extern "C" void kernel_launch(void* const* d_in, const int* in_sizes, int n_in,
                              void* d_out, int out_size, void* d_ws, size_t ws_size,
                              hipStream_t stream) {
    const float* x   = (const float*)d_in[0];
    const int*   dur = (const int*)d_in[1];

    const int B = LR_B;
    const int T = in_sizes[1] / B;                      // 512
    const int D = in_sizes[0] / in_sizes[1];            // 384
    const int max_len = (out_size / B - 1) / D;         // 3584
    const int D4 = D / 4;                               // 96
    const int tot = max_len * D4;                       // 344064 per batch

    float* out     = (float*)d_out;
    float* mel_out = out + (size_t)B * max_len * D;     // last B floats

    if (T == LR_T && D4 == 96 && (tot % 8192) == 0) {
        dim3 grid(tot / 8192, B, 1);                    // 42 x 32 = 1344 blocks
        lr_fused_kernel<96><<<grid, dim3(256, 1, 1), 0, stream>>>(
            (const f32x4*)x, dur, (f32x4*)d_out, mel_out, T, max_len);
    } else {
        int* idx = (int*)d_ws;                          // B*max_len ints
        lr_scan_idx_kernel<<<B, T, 0, stream>>>(dur, idx, mel_out, T, max_len);
        dim3 grid((tot + 255) / 256, B, 1);
        lr_copy_generic<<<grid, dim3(256, 1, 1), 0, stream>>>(
            (const f32x4*)x, idx, (f32x4*)d_out, T, max_len, D4);
    }
}

// Round 8
// 37.875 us; speedup vs baseline: 1.1526x; 1.1526x over previous
//
#include <hip/hip_runtime.h>

// Length regulator (fully fused, single kernel):
//   out[b, m, :] = x[b, searchsorted_right(cum(duration[b]), m), :]  for m < mel_len[b]
//   out[b, m, :] = 0                                                 otherwise
//   mel_len[b]   = sum_t duration[b, t]   (stored as float in d_out tail)
//
// Geometry (from setup_inputs): B=32, T=512, D=384, max_len=3584.
//
// Ledger (block-count curve, fused kernel):
//   1344 blocks (32 f4/thr) = 43.7us | 5376 (8/thr, confounded) = 40.7
//   10752 (4/thr, R4)       = 35.15  | this round: 21504 (2/thr)
// More+smaller blocks win: scan prologue hides under other blocks' store
// drain; block turnover supplies memory-level parallelism. XCD swizzle (R6)
// and wave0-scan (R5) both regressed — reverted.

#define LR_B 32
#define LR_T 512

typedef float f32x4 __attribute__((ext_vector_type(4)));

// ---------------------------------------------------------------------------
// Fused kernel: block = (512-float4 chunk, batch). 256 threads, 2 f4/thread.
//  1. load 512 durations -> LDS, Hillis-Steele inclusive scan (2 elems/thread)
//  2. threads 0..NF-1 (NF<=7) binary-search the block's frames -> idx_s
//  3. unrolled x2 gather-copy, nontemporal streaming stores
// ---------------------------------------------------------------------------
template <int D4C>
__global__ __launch_bounds__(256) void lr_fused_kernel(
        const f32x4* __restrict__ x4,
        const int* __restrict__ dur,
        f32x4* __restrict__ out4,
        float* __restrict__ mel_out,
        int T, int max_len) {
    __shared__ int s[LR_T];
    __shared__ int idx_s[8];

    const int b  = blockIdx.y;
    const int bx = blockIdx.x;
    const int t  = threadIdx.x;

    // --- 1. scan of duration[b, :] (512 elems, 256 threads, 2 per thread) ---
    const int* __restrict__ db = dur + b * LR_T;
    s[t]       = db[t];
    s[t + 256] = db[t + 256];
    __syncthreads();
    #pragma unroll
    for (int off = 1; off < LR_T; off <<= 1) {
        const int p1 = t + 256;
        const int a0 = (t >= off) ? s[t - off] : 0;
        const int a1 = s[p1 - off];            // p1 >= 256 >= off always
        __syncthreads();
        s[t]  += a0;
        s[p1] += a1;
        __syncthreads();
    }
    const int total = s[LR_T - 1];

    if (bx == 0 && t == 0) {
        mel_out[b] = (float)total;             // exact: total <= 3584 << 2^24
    }

    // --- 2. per-block frame index cache ---
    const int e0 = bx * 512;                   // first float4 element of block
    const int m0 = e0 / D4C;                   // first frame touched
    const int m1 = (e0 + 511) / D4C;           // last frame touched
    const int NF = m1 - m0 + 1;                // <= 7 for D4C==96
    if (t < NF) {
        const int m = m0 + t;
        int r = -1;
        if (m < total) {
            int lo = 0, hi = T;
            while (lo < hi) {                  // searchsorted side='right'
                const int mid = (lo + hi) >> 1;
                if (s[mid] <= m) lo = mid + 1; else hi = mid;
            }
            r = (lo < T) ? lo : (T - 1);
        }
        idx_s[t] = r;
    }
    __syncthreads();

    // --- 3. gather-copy: 2 float4s per thread, coalesced, streaming stores ---
    const f32x4* __restrict__ xb = x4 + (size_t)b * T * D4C;
    f32x4* __restrict__ ob = out4 + (size_t)b * (size_t)max_len * D4C;
    #pragma unroll
    for (int j = 0; j < 2; ++j) {
        const int e  = e0 + j * 256 + t;
        const int m  = e / D4C;                // compile-time divisor -> magic-mul
        const int d4 = e - m * D4C;
        const int id = idx_s[m - m0];          // LDS broadcast across lanes
        f32x4 v = (f32x4){0.f, 0.f, 0.f, 0.f};
        if (id >= 0) v = xb[id * D4C + d4];
        __builtin_nontemporal_store(v, &ob[e]);
    }
}

// ---------------------------------------------------------------------------
// Generic fallback path (runtime geometry), two kernels as in R2.
// ---------------------------------------------------------------------------
__global__ void lr_scan_idx_kernel(const int* __restrict__ dur,
                                   int* __restrict__ idx,
                                   float* __restrict__ mel_out,
                                   int T, int max_len) {
    __shared__ int s[LR_T];
    const int b = blockIdx.x;
    const int t = threadIdx.x;
    s[t] = dur[b * T + t];
    __syncthreads();
    #pragma unroll
    for (int off = 1; off < LR_T; off <<= 1) {
        int add = (t >= off) ? s[t - off] : 0;
        __syncthreads();
        s[t] += add;
        __syncthreads();
    }
    const int total = s[T - 1];
    if (t == 0) mel_out[b] = (float)total;
    int* __restrict__ idxb = idx + b * max_len;
    for (int m = t; m < max_len; m += LR_T) {
        int r = -1;
        if (m < total) {
            int lo = 0, hi = T;
            while (lo < hi) {
                int mid = (lo + hi) >> 1;
                if (s[mid] <= m) lo = mid + 1; else hi = mid;
            }
            r = (lo < T) ? lo : (T - 1);
        }
        idxb[m] = r;
    }
}

__global__ void lr_copy_generic(const f32x4* __restrict__ x4,
                                const int* __restrict__ idx,
                                f32x4* __restrict__ out4,
                                int T, int max_len, int D4) {
    const int b = blockIdx.y;
    const int tot = max_len * D4;
    const int e = blockIdx.x * blockDim.x + threadIdx.x;
    if (e >= tot) return;
    const int m  = e / D4;
    const int d4 = e - m * D4;
    const int id = idx[b * max_len + m];
    f32x4 v = (f32x4){0.f, 0.f, 0.f, 0.f};
    if (id >= 0) v = x4[((size_t)b * T + id) * D4 + d4];
    out4[(size_t)b * tot + e] = v;
}

extern "C" void kernel_launch(void* const* d_in, const int* in_sizes, int n_in,
                              void* d_out, int out_size, void* d_ws, size_t ws_size,
                              hipStream_t stream) {
    const float* x   = (const float*)d_in[0];
    const int*   dur = (const int*)d_in[1];

    const int B = LR_B;
    const int T = in_sizes[1] / B;                      // 512
    const int D = in_sizes[0] / in_sizes[1];            // 384
    const int max_len = (out_size / B - 1) / D;         // 3584
    const int D4 = D / 4;                               // 96
    const int tot = max_len * D4;                       // 344064 per batch

    float* out     = (float*)d_out;
    float* mel_out = out + (size_t)B * max_len * D;     // last B floats

    if (T == LR_T && D4 == 96 && (tot % 512) == 0) {
        dim3 grid(tot / 512, B, 1);                     // 672 x 32 = 21504 blocks
        lr_fused_kernel<96><<<grid, dim3(256, 1, 1), 0, stream>>>(
            (const f32x4*)x, dur, (f32x4*)d_out, mel_out, T, max_len);
    } else {
        int* idx = (int*)d_ws;                          // B*max_len ints
        lr_scan_idx_kernel<<<B, T, 0, stream>>>(dur, idx, mel_out, T, max_len);
        dim3 grid((tot + 255) / 256, B, 1);
        lr_copy_generic<<<grid, dim3(256, 1, 1), 0, stream>>>(
            (const f32x4*)x, idx, (f32x4*)d_out, T, max_len, D4);
    }
}

// Round 9
// 35.276 us; speedup vs baseline: 1.2375x; 1.0737x over previous
//
#include <hip/hip_runtime.h>

// Length regulator (fully fused, single kernel):
//   out[b, m, :] = x[b, searchsorted_right(cum(duration[b]), m), :]  for m < mel_len[b]
//   out[b, m, :] = 0                                                 otherwise
//   mel_len[b]   = sum_t duration[b, t]   (stored as float in d_out tail)
//
// Geometry (from setup_inputs): B=32, T=512, D=384, max_len=3584.
//
// Ledger (block-count curve, Hillis-Steele scan, 18 barriers):
//   1344=43.7 | 5376=40.7 | 10752=35.15 (best, R4) | 21504=37.9
// R6 XCD swizzle REGRESS (37.2). R9: keep the 10752-block knee, replace the
// 18-barrier LDS scan with a wave-REDUNDANT register shuffle scan: every wave
// computes the full 512-prefix independently (2x int4 load + 7 adds + 6
// shfl_up), writes its 128-elem quarter to LDS. 1 barrier, no idle lanes.

#define LR_B 32
#define LR_T 512

typedef float f32x4 __attribute__((ext_vector_type(4)));

// ---------------------------------------------------------------------------
// Fused kernel: block = (1024-float4 chunk, batch). 256 threads = 4 waves.
//  1. per-wave redundant shuffle scan of duration[b,:] -> LDS cum (1 barrier)
//  2. threads 0..NF-1 (NF<=12) binary-search the block's frames -> idx_s
//  3. unrolled x4 gather-copy, nontemporal streaming stores
// ---------------------------------------------------------------------------
template <int D4C>
__global__ __launch_bounds__(256) void lr_fused_kernel(
        const f32x4* __restrict__ x4,
        const int* __restrict__ dur,
        f32x4* __restrict__ out4,
        float* __restrict__ mel_out,
        int T, int max_len) {
    __shared__ int s[LR_T];
    __shared__ int idx_s[16];

    const int b  = blockIdx.y;
    const int bx = blockIdx.x;
    const int t  = threadIdx.x;
    const int w  = t >> 6;                     // wave id 0..3
    const int l  = t & 63;                     // lane id

    // --- 1. wave-redundant shuffle scan (each wave scans all 512 durs) ---
    {
        const int* __restrict__ db = dur + b * LR_T;
        const int4 a = *(const int4*)(db + l * 8);
        const int4 c = *(const int4*)(db + l * 8 + 4);
        const int v0 = a.x,      v1 = v0 + a.y, v2 = v1 + a.z, v3 = v2 + a.w;
        const int v4 = v3 + c.x, v5 = v4 + c.y, v6 = v5 + c.z, v7 = v6 + c.w;
        const int tot = v7;
        int pre = tot;                         // inclusive scan of lane totals
        #pragma unroll
        for (int off = 1; off < 64; off <<= 1) {
            const int u = __shfl_up(pre, off);
            if (l >= off) pre += u;
        }
        const int ex = pre - tot;              // exclusive prefix for this lane
        // wave w owns quarter [128w, 128(w+1)) = lanes 16w..16w+15's elems
        if ((l >> 4) == w) {
            int4 lo4 = make_int4(ex + v0, ex + v1, ex + v2, ex + v3);
            int4 hi4 = make_int4(ex + v4, ex + v5, ex + v6, ex + v7);
            *(int4*)&s[l * 8]     = lo4;
            *(int4*)&s[l * 8 + 4] = hi4;
        }
        if (bx == 0 && t == 63) {
            mel_out[b] = (float)pre;           // total; exact (<= 3584)
        }
    }
    __syncthreads();
    const int total = s[LR_T - 1];

    // --- 2. per-block frame index cache ---
    const int e0 = bx * 1024;                  // first float4 element of block
    const int m0 = e0 / D4C;                   // first frame touched
    const int m1 = (e0 + 1023) / D4C;          // last frame touched
    const int NF = m1 - m0 + 1;                // <= 12 for D4C==96
    if (t < NF) {
        const int m = m0 + t;
        int r = -1;
        if (m < total) {
            int lo = 0, hi = T;
            while (lo < hi) {                  // searchsorted side='right'
                const int mid = (lo + hi) >> 1;
                if (s[mid] <= m) lo = mid + 1; else hi = mid;
            }
            r = (lo < T) ? lo : (T - 1);
        }
        idx_s[t] = r;
    }
    __syncthreads();

    // --- 3. gather-copy: 4 float4s per thread, coalesced, streaming stores ---
    const f32x4* __restrict__ xb = x4 + (size_t)b * T * D4C;
    f32x4* __restrict__ ob = out4 + (size_t)b * (size_t)max_len * D4C;
    #pragma unroll
    for (int j = 0; j < 4; ++j) {
        const int e  = e0 + j * 256 + t;
        const int m  = e / D4C;                // compile-time divisor -> magic-mul
        const int d4 = e - m * D4C;
        const int id = idx_s[m - m0];          // LDS broadcast across lanes
        f32x4 v = (f32x4){0.f, 0.f, 0.f, 0.f};
        if (id >= 0) v = xb[id * D4C + d4];
        __builtin_nontemporal_store(v, &ob[e]);
    }
}

// ---------------------------------------------------------------------------
// Generic fallback path (runtime geometry), two kernels as in R2.
// ---------------------------------------------------------------------------
__global__ void lr_scan_idx_kernel(const int* __restrict__ dur,
                                   int* __restrict__ idx,
                                   float* __restrict__ mel_out,
                                   int T, int max_len) {
    __shared__ int s[LR_T];
    const int b = blockIdx.x;
    const int t = threadIdx.x;
    s[t] = dur[b * T + t];
    __syncthreads();
    #pragma unroll
    for (int off = 1; off < LR_T; off <<= 1) {
        int add = (t >= off) ? s[t - off] : 0;
        __syncthreads();
        s[t] += add;
        __syncthreads();
    }
    const int total = s[T - 1];
    if (t == 0) mel_out[b] = (float)total;
    int* __restrict__ idxb = idx + b * max_len;
    for (int m = t; m < max_len; m += LR_T) {
        int r = -1;
        if (m < total) {
            int lo = 0, hi = T;
            while (lo < hi) {
                int mid = (lo + hi) >> 1;
                if (s[mid] <= m) lo = mid + 1; else hi = mid;
            }
            r = (lo < T) ? lo : (T - 1);
        }
        idxb[m] = r;
    }
}

__global__ void lr_copy_generic(const f32x4* __restrict__ x4,
                                const int* __restrict__ idx,
                                f32x4* __restrict__ out4,
                                int T, int max_len, int D4) {
    const int b = blockIdx.y;
    const int tot = max_len * D4;
    const int e = blockIdx.x * blockDim.x + threadIdx.x;
    if (e >= tot) return;
    const int m  = e / D4;
    const int d4 = e - m * D4;
    const int id = idx[b * max_len + m];
    f32x4 v = (f32x4){0.f, 0.f, 0.f, 0.f};
    if (id >= 0) v = x4[((size_t)b * T + id) * D4 + d4];
    out4[(size_t)b * tot + e] = v;
}

extern "C" void kernel_launch(void* const* d_in, const int* in_sizes, int n_in,
                              void* d_out, int out_size, void* d_ws, size_t ws_size,
                              hipStream_t stream) {
    const float* x   = (const float*)d_in[0];
    const int*   dur = (const int*)d_in[1];

    const int B = LR_B;
    const int T = in_sizes[1] / B;                      // 512
    const int D = in_sizes[0] / in_sizes[1];            // 384
    const int max_len = (out_size / B - 1) / D;         // 3584
    const int D4 = D / 4;                               // 96
    const int tot = max_len * D4;                       // 344064 per batch

    float* out     = (float*)d_out;
    float* mel_out = out + (size_t)B * max_len * D;     // last B floats

    if (T == LR_T && D4 == 96 && (tot % 1024) == 0) {
        dim3 grid(tot / 1024, B, 1);                    // 336 x 32 = 10752 blocks
        lr_fused_kernel<96><<<grid, dim3(256, 1, 1), 0, stream>>>(
            (const f32x4*)x, dur, (f32x4*)d_out, mel_out, T, max_len);
    } else {
        int* idx = (int*)d_ws;                          // B*max_len ints
        lr_scan_idx_kernel<<<B, T, 0, stream>>>(dur, idx, mel_out, T, max_len);
        dim3 grid((tot + 255) / 256, B, 1);
        lr_copy_generic<<<grid, dim3(256, 1, 1), 0, stream>>>(
            (const f32x4*)x, idx, (f32x4*)d_out, T, max_len, D4);
    }
}